// Round 5
// baseline (571.256 us; speedup 1.0000x reference)
//
#include <hip/hip_runtime.h>
#include <hip/hip_cooperative_groups.h>
#include <cmath>
#include <complex>
#include <algorithm>

namespace cg = cooperative_groups;

#define CAP_S 512    // max edges out of Co (Poisson(12) max over 50k nodes ~35)
#define CAP_T 512    // max distinct targets of Co's edges
#define TB 256
#define MAX_BPCU 4   // conservative co-residency cap: 4 blocks/CU = 16 waves/CU

// ====================== host-side Wigner 3j (exact port, runs at .so load) =====================
namespace w3jhost {
static double fact(int n){
  static const double f[13]={1,1,2,6,24,120,720,5040,40320,362880,3628800,39916800,479001600};
  return f[n];
}
static double su2_cg(int j1,int m1,int j2,int m2,int j3,int m3){
  if(m3!=m1+m2) return 0.0;
  int vmin = std::max(std::max(-j1+j2+m3,-j1+m1),0);
  int vmax = std::min(std::min(j2+j3+m1, j3-j1+j2), j3+m3);
  double C = std::sqrt((double)(2*j3+1)*fact(j3+j1-j2)*fact(j3-j1+j2)*fact(j1+j2-j3)*fact(j3+m3)*fact(j3-m3)
            /(fact(j1+j2+j3+1)*fact(j1-m1)*fact(j1+m1)*fact(j2-m2)*fact(j2+m2)));
  double S=0.0;
  for(int v=vmin;v<=vmax;v++){
    double sgn = ((v+j2+m2)&1)?-1.0:1.0;
    S += sgn/fact(v)*fact(j2+j3+m1-v)*fact(j1-m1+v)/fact(j3-j1+j2-v)/fact(j3+m3-v)/fact(v+j1-j2-m3);
  }
  return C*S;
}
static void real_basis(int l, std::complex<double> q[7][7]){
  for(int i=0;i<7;i++)for(int j=0;j<7;j++) q[i][j]=0.0;
  const double r = std::sqrt(0.5);
  for(int m=-l;m<0;m++){ q[l+m][l-m]=r; q[l+m][l+m]=std::complex<double>(0.0,-r); }
  q[l][l]=1.0;
  for(int m=1;m<=l;m++){ double sg=(m&1)?-1.0:1.0; q[l+m][l+m]=sg*r; q[l+m][l-m]=std::complex<double>(0.0,sg*r); }
  std::complex<double> f;
  switch(l&3){ case 0: f={1,0};break; case 1: f={0,-1};break; case 2: f={-1,0};break; default: f={0,1};break; }
  for(int i=0;i<7;i++)for(int j=0;j<7;j++) q[i][j]*=f;
}
} // namespace w3jhost

struct W3JArg { float w[675]; };  // 7 paths concatenated, layout [i*(2l2+1)+j]*5+k

static W3JArg compute_w3j(){
  using namespace w3jhost;
  W3JArg out{};
  const int pl1[7]={0,1,1,2,2,3,3}, pl2[7]={2,1,3,0,2,1,3};
  int off=0;
  for(int p=0;p<7;p++){
    int l1=pl1[p], l2=pl2[p], l3=2;
    int n1=2*l1+1, n2=2*l2+1, n3=2*l3+1;
    double C[7][7][5];
    for(int i=0;i<7;i++)for(int k=0;k<7;k++)for(int n=0;n<5;n++) C[i][k][n]=0.0;
    for(int m1=-l1;m1<=l1;m1++)for(int m2=-l2;m2<=l2;m2++)
      if(std::abs(m1+m2)<=l3) C[l1+m1][l2+m2][l3+m1+m2]=su2_cg(l1,m1,l2,m2,l3,m1+m2);
    std::complex<double> Q1[7][7],Q2[7][7],Q3[7][7];
    real_basis(l1,Q1); real_basis(l2,Q2); real_basis(l3,Q3);
    double Cr[7][7][5]; double nrm=0.0;
    for(int a=0;a<n1;a++)for(int b=0;b<n2;b++)for(int c=0;c<n3;c++){
      std::complex<double> s(0.0,0.0);
      for(int i=0;i<n1;i++)for(int k=0;k<n2;k++)for(int n=0;n<n3;n++){
        double cv=C[i][k][n]; if(cv==0.0) continue;
        s += Q1[i][a]*Q2[k][b]*std::conj(Q3[n][c])*cv;  // einsum 'ij,kl,mn,ikn->jlm'
      }
      Cr[a][b][c]=s.real(); nrm+=s.real()*s.real();
    }
    nrm=std::sqrt(nrm);
    for(int a=0;a<n1;a++)for(int b=0;b<n2;b++)for(int c=0;c<n3;c++)
      out.w[off+(a*n2+b)*n3+c]=(float)(Cr[a][b][c]/nrm);
    off+=n1*n2*n3;
  }
  return out;
}
static const W3JArg g_w3j = compute_w3j();  // constant data; same every call

// ====================== device helpers ======================
__device__ __forceinline__ void calc_sh(float x,float y,float z,float* sh){
  float x2=x*x,y2=y*y,z2=z*z;
  const float s3=1.7320508075688772f, s5=2.2360679774997896f, s15=3.872983346207417f;
  const float s70_4=2.091650066335189f, s105=10.246950765959598f, s42_4=1.6201851746019651f;
  const float s7_2=1.3228756555322954f, s105_2=5.123475382979799f;
  sh[0]=1.f;
  sh[1]=s3*x; sh[2]=s3*y; sh[3]=s3*z;
  sh[4]=s15*x*z; sh[5]=s15*x*y; sh[6]=s5*(y2-0.5f*(x2+z2)); sh[7]=s15*y*z; sh[8]=0.5f*s15*(z2-x2);
  sh[9]=s70_4*x*(3.f*z2-x2); sh[10]=s105*x*y*z; sh[11]=s42_4*x*(5.f*y2-1.f);
  sh[12]=s7_2*y*(5.f*y2-3.f); sh[13]=s42_4*z*(5.f*y2-1.f); sh[14]=s105_2*y*(z2-x2); sh[15]=s70_4*z*(z2-3.f*x2);
}

// per-edge "mid" contribution, atomically accumulated into one node_mid row
__device__ __forceinline__ void mid_pipeline(const float* __restrict__ x, const float* __restrict__ pos,
                                             const float* __restrict__ W1, const float* __restrict__ W2,
                                             int a, int b, float* __restrict__ nm){
  float dx=pos[3*b]-pos[3*a], dy=pos[3*b+1]-pos[3*a+1], dz=pos[3*b+2]-pos[3*a+2];
  float d=sqrtf(dx*dx+dy*dy+dz*dz);
  float inv=1.f/d;
  float sh[16]; calc_sh(dx*inv,dy*inv,dz*inv,sh);
  float emb[20];
  const float step=3.5f/21.f;
  const float pref=(float)(1.14136*7.3890560989306495);  // 1.14136*e^2
  #pragma unroll
  for(int i=0;i<20;i++){
    float t=(d-(float)(i+1)*step)/step;
    float A=t+1.f, B=1.f-t;
    float ua=(A>0.f)?expf(-1.f/A):0.f;
    float ub=(B>0.f)?expf(-1.f/B):0.f;
    emb[i]=pref*ua*ub;
  }
  float h[30];
  #pragma unroll
  for(int j=0;j<30;j++){
    float z=0.f;
    #pragma unroll
    for(int i=0;i<20;i++) z+=emb[i]*W1[i*30+j];
    z*=0.22360679774997896f;         // 1/sqrt(20)
    h[j]=1.679177f*z/(1.f+expf(-z)); // NORM2MOM_SILU * silu
  }
  float tw[20];
  #pragma unroll
  for(int c=0;c<20;c++){
    float t=0.f;
    #pragma unroll
    for(int j=0;j<30;j++) t+=h[j]*W2[j*20+c];
    tw[c]=t*0.18257418583505536f;    // 1/sqrt(30)
  }
  float s=x[b];
  const float isq6=0.4082482904638631f;  // 1/sqrt(num_neighbors)
  #pragma unroll
  for(int l=0;l<4;l++){
    const int offs[4]={0,5,20,45}, shoff[4]={0,1,4,9};
    #pragma unroll
    for(int u=0;u<5;u++){
      float cfac=s*tw[l*5+u]*isq6;
      #pragma unroll
      for(int mm=0;mm<2*l+1;mm++)
        atomicAdd(&nm[offs[l]+u*(2*l+1)+mm], cfac*sh[shoff[l]+mm]);
    }
  }
}

// ====================== fused cooperative kernel (primary path) ======================
__global__ void __launch_bounds__(TB)
k_fused(const float* __restrict__ x, const float* __restrict__ pos,
        const int* __restrict__ efrom, const int* __restrict__ eto,
        const float* __restrict__ W1, const float* __restrict__ W2,
        const float* __restrict__ tp2,
        int N, int E,
        int* __restrict__ counts, int* __restrict__ slotof,
        unsigned long long* __restrict__ packed,
        int* __restrict__ numS, int* __restrict__ numT,
        int* __restrict__ Slist, float* __restrict__ node_mid,
        W3JArg w3, float* __restrict__ out5){
  cg::grid_group grid = cg::this_grid();
  const int T = gridDim.x*blockDim.x;
  const int tid = blockIdx.x*blockDim.x+threadIdx.x;

  // ---- phase 0: zero workspace ----
  for(int i=tid;i<N;i+=T){ counts[i]=0; slotof[i]=0; }
  if(tid==0){ *numS=0; *numT=0; *packed=0ull; }
  grid.sync();

  // ---- phase A: bincount(edge_to), streaming coalesced ----
  for(int e=tid;e<E;e+=T) atomicAdd(&counts[eto[e]],1);
  grid.sync();

  // ---- phase B: argmax with numpy first-index tie-break ----
  __shared__ unsigned long long sm;
  if(threadIdx.x==0) sm=0ull;
  __syncthreads();
  unsigned long long best=0ull;
  for(int i=tid;i<N;i+=T){
    unsigned long long v=(((unsigned long long)(unsigned)counts[i])<<32)
                        |(unsigned long long)(0xFFFFFFFFu-(unsigned)i);
    if(v>best) best=v;
  }
  if(best) atomicMax(&sm,best);
  __syncthreads();
  if(threadIdx.x==0 && sm) atomicMax(packed,sm);
  grid.sync();

  // ---- phase C: collect Co's out-edges; elect slots for target set ----
  const int co=(int)(0xFFFFFFFFu-(unsigned)((*packed)&0xFFFFFFFFull));
  for(int e=tid;e<E;e+=T){
    if(efrom[e]==co){
      int b=eto[e];
      int p=atomicAdd(numS,1);
      if(p<CAP_S) Slist[p]=b;
      if(atomicCAS(&slotof[b],0,-1)==0){      // winner zeroes row + assigns slot
        int s=atomicAdd(numT,1);
        if(s<CAP_T){
          float* nm=node_mid+(size_t)s*80;
          for(int q=0;q<80;q++) nm[q]=0.f;
          slotof[b]=s+1;
        } else slotof[b]=0;
      }
    }
  }
  grid.sync();

  // ---- phase D: mid pipeline for edges whose source is in target set ----
  for(int e=tid;e<E;e+=T){
    int a=efrom[e];                 // coalesced, L2/L3-warm from phase C
    int s=slotof[a];                // L2-resident gather (200 KB table)
    if(s>=1)                        // ~144 of 600k edges survive
      mid_pipeline(x,pos,W1,W2,a,eto[e],node_mid+(size_t)(s-1)*80);
  }
  grid.sync();

  // ---- phase E: second tensor product over Co's edges, reduce to 5 floats ----
  if(blockIdx.x==0){
    __shared__ float acc[5];
    if(threadIdx.x<5) acc[threadIdx.x]=0.f;
    __syncthreads();
    int ns=*numS; if(ns>CAP_S) ns=CAP_S;
    const int pl1[7]={0,1,1,2,2,3,3}, pl2[7]={2,1,3,0,2,1,3};
    const int wbase[7]={0,25,70,175,200,325,430};
    const int offs[4]={0,5,20,45}, shoff[4]={0,1,4,9};
    for(int t=threadIdx.x;t<ns;t+=blockDim.x){
      int b=Slist[t];
      int s=slotof[b];
      if(s<1) continue;
      const float* m=node_mid+(size_t)(s-1)*80;
      float dx=pos[3*b]-pos[3*co], dy=pos[3*b+1]-pos[3*co+1], dz=pos[3*b+2]-pos[3*co+2];
      float d=sqrtf(dx*dx+dy*dy+dz*dz), inv=1.f/d;
      float sh[16]; calc_sh(dx*inv,dy*inv,dz*inv,sh);
      float o[5]={0.f,0.f,0.f,0.f,0.f};
      for(int p=0;p<7;p++){
        int l1=pl1[p], l2=pl2[p];
        int n1=2*l1+1, n2=2*l2+1;
        const float* W=w3.w+wbase[p];
        for(int u=0;u<5;u++){
          float tu=tp2[p*5+u];
          for(int i=0;i<n1;i++){
            float mi=m[offs[l1]+u*n1+i]*tu;
            for(int j=0;j<n2;j++){
              float c=mi*sh[shoff[l2]+j];
              const float* Wk=W+(i*n2+j)*5;
              for(int kk=0;kk<5;kk++) o[kk]+=Wk[kk]*c;
            }
          }
        }
      }
      for(int kk=0;kk<5;kk++) atomicAdd(&acc[kk],o[kk]);
    }
    __syncthreads();
    const float scale=0.37796447300922725f*0.4082482904638631f;  // ALPHA2 * 1/sqrt(6)
    if(threadIdx.x<5) out5[threadIdx.x]=acc[threadIdx.x]*scale;
  }
}

// ====================== fallback kernels (round-1 verified path) ======================
__global__ void k_bincount(const int* __restrict__ eto, int E, int* __restrict__ counts){
  int e=blockIdx.x*blockDim.x+threadIdx.x;
  if(e<E) atomicAdd(&counts[eto[e]],1);
}

__global__ void k_argmax(const int* __restrict__ counts, int N, unsigned long long* __restrict__ packed){
  __shared__ unsigned long long sm;
  if(threadIdx.x==0) sm=0ull;
  __syncthreads();
  int i=blockIdx.x*blockDim.x+threadIdx.x;
  unsigned long long v=0ull;
  if(i<N)
    v=(((unsigned long long)(unsigned)counts[i])<<32) | (unsigned long long)(0xFFFFFFFFu-(unsigned)i);
  atomicMax(&sm,v);
  __syncthreads();
  if(threadIdx.x==0) atomicMax(packed,sm);
}

__global__ void k_collect(const int* __restrict__ efrom, const int* __restrict__ eto, int E,
                          const unsigned long long* __restrict__ packed,
                          int* __restrict__ S, int* __restrict__ numS, int* __restrict__ flagslot){
  int e=blockIdx.x*blockDim.x+threadIdx.x;
  if(e>=E) return;
  int co=(int)(0xFFFFFFFFu-(unsigned)((*packed)&0xFFFFFFFFull));
  if(efrom[e]==co){
    int p=atomicAdd(numS,1);
    if(p<CAP_S) S[p]=e;
    flagslot[eto[e]]=1;
  }
}

__global__ void k_slots(int* __restrict__ flagslot, int N, int* __restrict__ numT){
  int v=blockIdx.x*blockDim.x+threadIdx.x;
  if(v>=N) return;
  if(flagslot[v]==1){
    int s=atomicAdd(numT,1);
    flagslot[v]=(s<CAP_T)?(s+2):0;
  }
}

__global__ void k_mid(const float* __restrict__ x, const float* __restrict__ pos,
                      const int* __restrict__ efrom, const int* __restrict__ eto,
                      const float* __restrict__ W1, const float* __restrict__ W2,
                      int E, const int* __restrict__ flagslot, float* __restrict__ node_mid){
  int e=blockIdx.x*blockDim.x+threadIdx.x;
  if(e>=E) return;
  int a=efrom[e];
  int fs=flagslot[a];
  if(fs<2) return;
  mid_pipeline(x,pos,W1,W2,a,eto[e],node_mid+(size_t)(fs-2)*80);
}

__global__ void k_final(const float* __restrict__ pos, const int* __restrict__ efrom,
                        const int* __restrict__ eto, const float* __restrict__ tp2,
                        const int* __restrict__ flagslot, const float* __restrict__ node_mid,
                        const int* __restrict__ S, const int* __restrict__ numS,
                        W3JArg w3, float* __restrict__ out5){
  __shared__ float acc[5];
  if(threadIdx.x<5) acc[threadIdx.x]=0.f;
  __syncthreads();
  int ns=*numS; if(ns>CAP_S) ns=CAP_S;
  const int pl1[7]={0,1,1,2,2,3,3}, pl2[7]={2,1,3,0,2,1,3};
  const int wbase[7]={0,25,70,175,200,325,430};
  const int offs[4]={0,5,20,45}, shoff[4]={0,1,4,9};
  for(int t=threadIdx.x;t<ns;t+=blockDim.x){
    int e=S[t];
    int a=efrom[e], b=eto[e];
    int fs=flagslot[b];
    if(fs<2) continue;
    const float* m=node_mid+(size_t)(fs-2)*80;
    float dx=pos[3*b]-pos[3*a], dy=pos[3*b+1]-pos[3*a+1], dz=pos[3*b+2]-pos[3*a+2];
    float d=sqrtf(dx*dx+dy*dy+dz*dz), inv=1.f/d;
    float sh[16]; calc_sh(dx*inv,dy*inv,dz*inv,sh);
    float o[5]={0.f,0.f,0.f,0.f,0.f};
    for(int p=0;p<7;p++){
      int l1=pl1[p], l2=pl2[p];
      int n1=2*l1+1, n2=2*l2+1;
      const float* W=w3.w+wbase[p];
      for(int u=0;u<5;u++){
        float tu=tp2[p*5+u];
        for(int i=0;i<n1;i++){
          float mi=m[offs[l1]+u*n1+i]*tu;
          for(int j=0;j<n2;j++){
            float c=mi*sh[shoff[l2]+j];
            const float* Wk=W+(i*n2+j)*5;
            for(int k=0;k<5;k++) o[k]+=Wk[k]*c;
          }
        }
      }
    }
    for(int k=0;k<5;k++) atomicAdd(&acc[k],o[k]);
  }
  __syncthreads();
  const float scale=0.37796447300922725f*0.4082482904638631f;  // ALPHA2 * 1/sqrt(6)
  if(threadIdx.x<5) out5[threadIdx.x]=acc[threadIdx.x]*scale;
}

// ====================== launch ======================
extern "C" void kernel_launch(void* const* d_in, const int* in_sizes, int n_in,
                              void* d_out, int out_size, void* d_ws, size_t ws_size,
                              hipStream_t stream){
  const float* x    =(const float*)d_in[0];
  const float* pos  =(const float*)d_in[1];
  const int*   efrom=(const int*)  d_in[2];
  const int*   eto  =(const int*)  d_in[3];
  const float* W1   =(const float*)d_in[4];
  const float* W2   =(const float*)d_in[5];
  const float* tp2  =(const float*)d_in[6];
  int N=in_sizes[0], E=in_sizes[2];

  char* ws=(char*)d_ws;
  size_t o=0;
  int* counts=(int*)(ws+o);                 o+=(size_t)N*4;
  int* slotof=(int*)(ws+o);                 o+=(size_t)N*4;
  o=(o+15)&~(size_t)15;
  unsigned long long* packed=(unsigned long long*)(ws+o); o+=8;
  int* numS=(int*)(ws+o);                   o+=4;
  int* numT=(int*)(ws+o);                   o+=4;
  o=(o+15)&~(size_t)15;
  int* Slist=(int*)(ws+o);                  o+=(size_t)CAP_S*4;
  float* node_mid=(float*)(ws+o);           o+=(size_t)CAP_T*80*4;

  float* outp=(float*)d_out;
  W3JArg* w3p=const_cast<W3JArg*>(&g_w3j);
  void* kargs[]={ (void*)&x,(void*)&pos,(void*)&efrom,(void*)&eto,(void*)&W1,(void*)&W2,(void*)&tp2,
                  (void*)&N,(void*)&E,
                  (void*)&counts,(void*)&slotof,(void*)&packed,(void*)&numS,(void*)&numT,
                  (void*)&Slist,(void*)&node_mid,(void*)w3p,(void*)&outp };

  // Size the cooperative grid from a pure occupancy query (capture-safe; no
  // trial launches — a FAILED launch inside graph capture invalidates it).
  int bpcu=0;
  hipError_t qrc = hipOccupancyMaxActiveBlocksPerMultiprocessor(&bpcu,(const void*)k_fused,TB,0);
  if(qrc!=hipSuccess||bpcu<1) bpcu=1;
  if(bpcu>MAX_BPCU) bpcu=MAX_BPCU;   // conservative: validator may be optimistic vs HW co-residency
  int ncu=0;
  if(hipDeviceGetAttribute(&ncu,hipDeviceAttributeMultiprocessorCount,0)!=hipSuccess||ncu<1) ncu=256;
  int NB=bpcu*ncu;

  hipError_t rc = hipLaunchCooperativeKernel((void*)k_fused, dim3(NB), dim3(TB), kargs, 0, stream);

  if(rc != hipSuccess){
    // ---- fallback: round-1 verified multi-kernel path ----
    hipMemsetAsync(d_ws,0,o,stream);
    const int tb=256;
    int gE=(E+tb-1)/tb, gN=(N+tb-1)/tb;
    k_bincount<<<gE,tb,0,stream>>>(eto,E,counts);
    k_argmax  <<<gN,tb,0,stream>>>(counts,N,packed);
    k_collect <<<gE,tb,0,stream>>>(efrom,eto,E,packed,Slist,numS,slotof);
    k_slots   <<<gN,tb,0,stream>>>(slotof,N,numT);
    k_mid     <<<gE,tb,0,stream>>>(x,pos,efrom,eto,W1,W2,E,slotof,node_mid);
    k_final   <<<1,64,0,stream>>>(pos,efrom,eto,tp2,slotof,node_mid,Slist,numS,g_w3j,outp);
  }
}

// Round 6
// 238.295 us; speedup vs baseline: 2.3973x; 2.3973x over previous
//
#include <hip/hip_runtime.h>
#include <cmath>
#include <complex>
#include <algorithm>

#define CAP_S 512    // max edges out of Co (Poisson(12) max over 50k nodes ~35)
#define CAP_T 512    // max distinct targets of Co's edges
#define TB 256
#define NBLK 256     // persistent grid-stride blocks: avoids the 32-blocks/us dispatch bound

// ====================== host-side Wigner 3j (exact port, runs at .so load) =====================
namespace w3jhost {
static double fact(int n){
  static const double f[13]={1,1,2,6,24,120,720,5040,40320,362880,3628800,39916800,479001600};
  return f[n];
}
static double su2_cg(int j1,int m1,int j2,int m2,int j3,int m3){
  if(m3!=m1+m2) return 0.0;
  int vmin = std::max(std::max(-j1+j2+m3,-j1+m1),0);
  int vmax = std::min(std::min(j2+j3+m1, j3-j1+j2), j3+m3);
  double C = std::sqrt((double)(2*j3+1)*fact(j3+j1-j2)*fact(j3-j1+j2)*fact(j1+j2-j3)*fact(j3+m3)*fact(j3-m3)
            /(fact(j1+j2+j3+1)*fact(j1-m1)*fact(j1+m1)*fact(j2-m2)*fact(j2+m2)));
  double S=0.0;
  for(int v=vmin;v<=vmax;v++){
    double sgn = ((v+j2+m2)&1)?-1.0:1.0;
    S += sgn/fact(v)*fact(j2+j3+m1-v)*fact(j1-m1+v)/fact(j3-j1+j2-v)/fact(j3+m3-v)/fact(v+j1-j2-m3);
  }
  return C*S;
}
static void real_basis(int l, std::complex<double> q[7][7]){
  for(int i=0;i<7;i++)for(int j=0;j<7;j++) q[i][j]=0.0;
  const double r = std::sqrt(0.5);
  for(int m=-l;m<0;m++){ q[l+m][l-m]=r; q[l+m][l+m]=std::complex<double>(0.0,-r); }
  q[l][l]=1.0;
  for(int m=1;m<=l;m++){ double sg=(m&1)?-1.0:1.0; q[l+m][l+m]=sg*r; q[l+m][l-m]=std::complex<double>(0.0,sg*r); }
  std::complex<double> f;
  switch(l&3){ case 0: f={1,0};break; case 1: f={0,-1};break; case 2: f={-1,0};break; default: f={0,1};break; }
  for(int i=0;i<7;i++)for(int j=0;j<7;j++) q[i][j]*=f;
}
} // namespace w3jhost

struct W3JArg { float w[675]; };  // 7 paths concatenated, layout [i*(2l2+1)+j]*5+k

static W3JArg compute_w3j(){
  using namespace w3jhost;
  W3JArg out{};
  const int pl1[7]={0,1,1,2,2,3,3}, pl2[7]={2,1,3,0,2,1,3};
  int off=0;
  for(int p=0;p<7;p++){
    int l1=pl1[p], l2=pl2[p], l3=2;
    int n1=2*l1+1, n2=2*l2+1, n3=2*l3+1;
    double C[7][7][5];
    for(int i=0;i<7;i++)for(int k=0;k<7;k++)for(int n=0;n<5;n++) C[i][k][n]=0.0;
    for(int m1=-l1;m1<=l1;m1++)for(int m2=-l2;m2<=l2;m2++)
      if(std::abs(m1+m2)<=l3) C[l1+m1][l2+m2][l3+m1+m2]=su2_cg(l1,m1,l2,m2,l3,m1+m2);
    std::complex<double> Q1[7][7],Q2[7][7],Q3[7][7];
    real_basis(l1,Q1); real_basis(l2,Q2); real_basis(l3,Q3);
    double Cr[7][7][5]; double nrm=0.0;
    for(int a=0;a<n1;a++)for(int b=0;b<n2;b++)for(int c=0;c<n3;c++){
      std::complex<double> s(0.0,0.0);
      for(int i=0;i<n1;i++)for(int k=0;k<n2;k++)for(int n=0;n<n3;n++){
        double cv=C[i][k][n]; if(cv==0.0) continue;
        s += Q1[i][a]*Q2[k][b]*std::conj(Q3[n][c])*cv;  // einsum 'ij,kl,mn,ikn->jlm'
      }
      Cr[a][b][c]=s.real(); nrm+=s.real()*s.real();
    }
    nrm=std::sqrt(nrm);
    for(int a=0;a<n1;a++)for(int b=0;b<n2;b++)for(int c=0;c<n3;c++)
      out.w[off+(a*n2+b)*n3+c]=(float)(Cr[a][b][c]/nrm);
    off+=n1*n2*n3;
  }
  return out;
}
static const W3JArg g_w3j = compute_w3j();  // constant data; same every call

// ====================== device helpers ======================
__device__ __forceinline__ void calc_sh(float x,float y,float z,float* sh){
  float x2=x*x,y2=y*y,z2=z*z;
  const float s3=1.7320508075688772f, s5=2.2360679774997896f, s15=3.872983346207417f;
  const float s70_4=2.091650066335189f, s105=10.246950765959598f, s42_4=1.6201851746019651f;
  const float s7_2=1.3228756555322954f, s105_2=5.123475382979799f;
  sh[0]=1.f;
  sh[1]=s3*x; sh[2]=s3*y; sh[3]=s3*z;
  sh[4]=s15*x*z; sh[5]=s15*x*y; sh[6]=s5*(y2-0.5f*(x2+z2)); sh[7]=s15*y*z; sh[8]=0.5f*s15*(z2-x2);
  sh[9]=s70_4*x*(3.f*z2-x2); sh[10]=s105*x*y*z; sh[11]=s42_4*x*(5.f*y2-1.f);
  sh[12]=s7_2*y*(5.f*y2-3.f); sh[13]=s42_4*z*(5.f*y2-1.f); sh[14]=s105_2*y*(z2-x2); sh[15]=s70_4*z*(z2-3.f*x2);
}

// per-edge "mid" contribution, atomically accumulated into one node_mid row
__device__ __forceinline__ void mid_pipeline(const float* __restrict__ x, const float* __restrict__ pos,
                                             const float* __restrict__ W1, const float* __restrict__ W2,
                                             int a, int b, float* __restrict__ nm){
  float dx=pos[3*b]-pos[3*a], dy=pos[3*b+1]-pos[3*a+1], dz=pos[3*b+2]-pos[3*a+2];
  float d=sqrtf(dx*dx+dy*dy+dz*dz);
  float inv=1.f/d;
  float sh[16]; calc_sh(dx*inv,dy*inv,dz*inv,sh);
  float emb[20];
  const float step=3.5f/21.f;
  const float pref=(float)(1.14136*7.3890560989306495);  // 1.14136*e^2
  #pragma unroll
  for(int i=0;i<20;i++){
    float t=(d-(float)(i+1)*step)/step;
    float A=t+1.f, B=1.f-t;
    float ua=(A>0.f)?expf(-1.f/A):0.f;
    float ub=(B>0.f)?expf(-1.f/B):0.f;
    emb[i]=pref*ua*ub;
  }
  float h[30];
  #pragma unroll
  for(int j=0;j<30;j++){
    float z=0.f;
    #pragma unroll
    for(int i=0;i<20;i++) z+=emb[i]*W1[i*30+j];
    z*=0.22360679774997896f;         // 1/sqrt(20)
    h[j]=1.679177f*z/(1.f+expf(-z)); // NORM2MOM_SILU * silu
  }
  float tw[20];
  #pragma unroll
  for(int c=0;c<20;c++){
    float t=0.f;
    #pragma unroll
    for(int j=0;j<30;j++) t+=h[j]*W2[j*20+c];
    tw[c]=t*0.18257418583505536f;    // 1/sqrt(30)
  }
  float s=x[b];
  const float isq6=0.4082482904638631f;  // 1/sqrt(num_neighbors)
  #pragma unroll
  for(int l=0;l<4;l++){
    const int offs[4]={0,5,20,45}, shoff[4]={0,1,4,9};
    #pragma unroll
    for(int u=0;u<5;u++){
      float cfac=s*tw[l*5+u]*isq6;
      #pragma unroll
      for(int mm=0;mm<2*l+1;mm++)
        atomicAdd(&nm[offs[l]+u*(2*l+1)+mm], cfac*sh[shoff[l]+mm]);
    }
  }
}

// ====================== kernels (grid-stride persistent blocks) ======================
__global__ void k_bincount(const int* __restrict__ eto, int E, int* __restrict__ counts){
  int T=gridDim.x*blockDim.x;
  for(int e=blockIdx.x*blockDim.x+threadIdx.x;e<E;e+=T)
    atomicAdd(&counts[eto[e]],1);
}

__global__ void k_argmax(const int* __restrict__ counts, int N, unsigned long long* __restrict__ packed){
  __shared__ unsigned long long sm;
  if(threadIdx.x==0) sm=0ull;
  __syncthreads();
  int T=gridDim.x*blockDim.x;
  unsigned long long best=0ull;
  for(int i=blockIdx.x*blockDim.x+threadIdx.x;i<N;i+=T){
    unsigned long long v=(((unsigned long long)(unsigned)counts[i])<<32)
                        |(unsigned long long)(0xFFFFFFFFu-(unsigned)i);  // numpy first-index tie-break
    if(v>best) best=v;
  }
  if(best) atomicMax(&sm,best);
  __syncthreads();
  if(threadIdx.x==0 && sm) atomicMax(packed,sm);
}

// collect Co's out-edges + slot election + row zeroing, all in one pass over efrom
__global__ void k_collect(const int* __restrict__ efrom, const int* __restrict__ eto, int E,
                          const unsigned long long* __restrict__ packed,
                          int* __restrict__ Slist, int* __restrict__ numS, int* __restrict__ numT,
                          int* __restrict__ slotof, float* __restrict__ node_mid){
  int T=gridDim.x*blockDim.x;
  const int co=(int)(0xFFFFFFFFu-(unsigned)((*packed)&0xFFFFFFFFull));
  for(int e=blockIdx.x*blockDim.x+threadIdx.x;e<E;e+=T){
    if(efrom[e]==co){
      int b=eto[e];
      int p=atomicAdd(numS,1);
      if(p<CAP_S) Slist[p]=b;
      if(atomicCAS(&slotof[b],0,-1)==0){       // winner zeroes row + assigns slot
        int s=atomicAdd(numT,1);
        if(s<CAP_T){
          float* nm=node_mid+(size_t)s*80;
          for(int q=0;q<80;q++) nm[q]=0.f;
          __threadfence();                     // row zeros visible before slot publish
          slotof[b]=s+1;
        } else slotof[b]=0;
      }
    }
  }
}

__global__ void k_mid(const float* __restrict__ x, const float* __restrict__ pos,
                      const int* __restrict__ efrom, const int* __restrict__ eto,
                      const float* __restrict__ W1, const float* __restrict__ W2,
                      int E, const int* __restrict__ slotof, float* __restrict__ node_mid){
  int T=gridDim.x*blockDim.x;
  for(int e=blockIdx.x*blockDim.x+threadIdx.x;e<E;e+=T){
    int a=efrom[e];                 // coalesced stream
    int s=slotof[a];                // L2-resident gather (200 KB table)
    if(s>=1)                        // ~144 of 600k edges survive
      mid_pipeline(x,pos,W1,W2,a,eto[e],node_mid+(size_t)(s-1)*80);
  }
}

__global__ void k_final(const float* __restrict__ pos, const float* __restrict__ tp2,
                        const unsigned long long* __restrict__ packed,
                        const int* __restrict__ slotof, const float* __restrict__ node_mid,
                        const int* __restrict__ Slist, const int* __restrict__ numS,
                        W3JArg w3, float* __restrict__ out5){
  __shared__ float acc[5];
  if(threadIdx.x<5) acc[threadIdx.x]=0.f;
  __syncthreads();
  const int co=(int)(0xFFFFFFFFu-(unsigned)((*packed)&0xFFFFFFFFull));
  int ns=*numS; if(ns>CAP_S) ns=CAP_S;
  const int pl1[7]={0,1,1,2,2,3,3}, pl2[7]={2,1,3,0,2,1,3};
  const int wbase[7]={0,25,70,175,200,325,430};
  const int offs[4]={0,5,20,45}, shoff[4]={0,1,4,9};
  for(int t=threadIdx.x;t<ns;t+=blockDim.x){
    int b=Slist[t];
    int s=slotof[b];
    if(s<1) continue;
    const float* m=node_mid+(size_t)(s-1)*80;
    float dx=pos[3*b]-pos[3*co], dy=pos[3*b+1]-pos[3*co+1], dz=pos[3*b+2]-pos[3*co+2];
    float d=sqrtf(dx*dx+dy*dy+dz*dz), inv=1.f/d;
    float sh[16]; calc_sh(dx*inv,dy*inv,dz*inv,sh);
    float o[5]={0.f,0.f,0.f,0.f,0.f};
    for(int p=0;p<7;p++){
      int l1=pl1[p], l2=pl2[p];
      int n1=2*l1+1, n2=2*l2+1;
      const float* W=w3.w+wbase[p];
      for(int u=0;u<5;u++){
        float tu=tp2[p*5+u];
        for(int i=0;i<n1;i++){
          float mi=m[offs[l1]+u*n1+i]*tu;
          for(int j=0;j<n2;j++){
            float c=mi*sh[shoff[l2]+j];
            const float* Wk=W+(i*n2+j)*5;
            for(int kk=0;kk<5;kk++) o[kk]+=Wk[kk]*c;
          }
        }
      }
    }
    for(int kk=0;kk<5;kk++) atomicAdd(&acc[kk],o[kk]);
  }
  __syncthreads();
  const float scale=0.37796447300922725f*0.4082482904638631f;  // ALPHA2 * 1/sqrt(6)
  if(threadIdx.x<5) out5[threadIdx.x]=acc[threadIdx.x]*scale;
}

// ====================== launch ======================
extern "C" void kernel_launch(void* const* d_in, const int* in_sizes, int n_in,
                              void* d_out, int out_size, void* d_ws, size_t ws_size,
                              hipStream_t stream){
  const float* x    =(const float*)d_in[0];
  const float* pos  =(const float*)d_in[1];
  const int*   efrom=(const int*)  d_in[2];
  const int*   eto  =(const int*)  d_in[3];
  const float* W1   =(const float*)d_in[4];
  const float* W2   =(const float*)d_in[5];
  const float* tp2  =(const float*)d_in[6];
  int N=in_sizes[0], E=in_sizes[2];

  char* ws=(char*)d_ws;
  size_t o=0;
  int* counts=(int*)(ws+o);                 o+=(size_t)N*4;
  int* slotof=(int*)(ws+o);                 o+=(size_t)N*4;
  o=(o+15)&~(size_t)15;
  unsigned long long* packed=(unsigned long long*)(ws+o); o+=8;
  int* numS=(int*)(ws+o);                   o+=4;
  int* numT=(int*)(ws+o);                   o+=4;
  size_t zero_bytes=o;                      // control prefix needing zeros
  o=(o+15)&~(size_t)15;
  int* Slist=(int*)(ws+o);                  o+=(size_t)CAP_S*4;       // guarded by numS
  float* node_mid=(float*)(ws+o);           o+=(size_t)CAP_T*80*4;    // zeroed by k_collect winners

  hipMemsetAsync(d_ws,0,zero_bytes,stream);  // 400 KB control prefix, one DMA

  k_bincount<<<NBLK,TB,0,stream>>>(eto,E,counts);
  k_argmax  <<<NBLK,TB,0,stream>>>(counts,N,packed);
  k_collect <<<NBLK,TB,0,stream>>>(efrom,eto,E,packed,Slist,numS,numT,slotof,node_mid);
  k_mid     <<<NBLK,TB,0,stream>>>(x,pos,efrom,eto,W1,W2,E,slotof,node_mid);
  k_final   <<<1,64,0,stream>>>(pos,tp2,packed,slotof,node_mid,Slist,numS,g_w3j,(float*)d_out);
}